// Round 19
// baseline (230.118 us; speedup 1.0000x reference)
//
#include <hip/hip_runtime.h>
#include <hip/hip_bf16.h>

#define C 128
#define NBKT 128
#define BCAP 8192

typedef __bf16 bf16x8 __attribute__((ext_vector_type(8)));
typedef float floatx4 __attribute__((ext_vector_type(4)));

// ---- manual bf16 helpers ----
__device__ __forceinline__ unsigned short f2bf(float f) {
    unsigned u = __float_as_uint(f);
    unsigned r = (u + 0x7FFFu + ((u >> 16) & 1u)) >> 16;
    return (unsigned short)r;
}
__device__ __forceinline__ float bflo(unsigned v) { return __uint_as_float(v << 16); }
__device__ __forceinline__ float bfhi(unsigned v) { return __uint_as_float(v & 0xFFFF0000u); }
__device__ __forceinline__ unsigned packbf(float lo, float hi) {
    return (unsigned)f2bf(lo) | ((unsigned)f2bf(hi) << 16);
}

// ---- dtype-flexible accessors ----
__device__ __forceinline__ int g_idx(const void* p, long long i, int is64) {
    if (is64) return (int)((const long long*)p)[i];
    return ((const int*)p)[i];
}
__device__ __forceinline__ float g_flt(const void* p, long long i, int isf32) {
    if (isf32) return ((const float*)p)[i];
    return __uint_as_float(((unsigned)((const unsigned short*)p)[i]) << 16);
}

// flags + zero row N (both slices) of g0,g1,g2 + zero bucketcnt
__global__ void k_detect(const void* edge, const void* nid, const void* emb, int* flags,
                         unsigned* g0, unsigned* g1, unsigned* g2, int* bucketcnt,
                         int N, int SST) {
    int t = threadIdx.x;  // 192 threads
    int buf = t >> 6, w = t & 63;
    size_t o = (size_t)(w >> 5) * SST + (size_t)N * 32 + (w & 31);
    if (buf == 0) g0[o] = 0;
    else if (buf == 1) g1[o] = 0;
    else g2[o] = 0;
    if (t < NBKT) bucketcnt[t] = 0;
    if (t < 64) {
        const unsigned* wrd = (const unsigned*)edge;
        const unsigned* nw = (const unsigned*)nid;
        int predA = (t < 32) ? (wrd[2 * t + 1] == 0u) : 1;
        int predB = (t < 32) ? (nw[2 * t + 1] == 0u) : 1;
        const unsigned short* h = (const unsigned short*)emb;
        int ex = (h[2 * t] >> 7) & 0xFF;
        int plaus = (ex >= 0x6C && ex <= 0x7F) ? 1 : 0;
        unsigned long long mA = __ballot(predA);
        unsigned long long mB = __ballot(predB);
        unsigned long long mP = __ballot(plaus);
        if (t == 0) {
            flags[0] = (mA == ~0ull) ? 1 : 0;
            flags[1] = (mB == ~0ull) ? 1 : 0;
            flags[2] = (__popcll(mP) < 32) ? 1 : 0;
        }
    }
}

// -------- phase A: bucket edges into 128 row-ranges; vectorized edge loads --------
__global__ void k_bucketA(const void* edge, int E, int rpb, const int* flags,
                          unsigned* __restrict__ bucketbuf, int* __restrict__ bucketcnt) {
    __shared__ int lcnt[NBKT];
    __shared__ int lbase[NBKT];
    int t = threadIdx.x;
    int is64 = flags[0];
    const int PER = 8;
    int chunkSz = blockDim.x * PER;
    long long stride = (long long)gridDim.x * chunkSz;
    for (long long base = (long long)blockIdx.x * chunkSz; base < E; base += stride) {
        if (t < NBKT) lcnt[t] = 0;
        __syncthreads();
        int bkt[PER], rank[PER];
        unsigned enc[PER];
        long long e0 = base + (long long)t * PER;
        int rr[PER], cc[PER];
        if (e0 + PER <= E) {
            if (is64) {
                const long long* pr = (const long long*)edge + e0;
                const long long* pc = (const long long*)edge + E + e0;
#pragma unroll
                for (int j = 0; j < PER; j += 2) {
                    longlong2 vr = *(const longlong2*)(pr + j);
                    longlong2 vc = *(const longlong2*)(pc + j);
                    rr[j] = (int)vr.x; rr[j + 1] = (int)vr.y;
                    cc[j] = (int)vc.x; cc[j + 1] = (int)vc.y;
                }
            } else {
                const int* pr = (const int*)edge + e0;
                const int* pc = (const int*)edge + E + e0;
#pragma unroll
                for (int j = 0; j < PER; j += 4) {
                    int4 vr = *(const int4*)(pr + j);
                    int4 vc = *(const int4*)(pc + j);
                    rr[j] = vr.x; rr[j + 1] = vr.y; rr[j + 2] = vr.z; rr[j + 3] = vr.w;
                    cc[j] = vc.x; cc[j + 1] = vc.y; cc[j + 2] = vc.z; cc[j + 3] = vc.w;
                }
            }
#pragma unroll
            for (int j = 0; j < PER; ++j) {
                int b = rr[j] / rpb;
                bkt[j] = b;
                enc[j] = ((unsigned)(rr[j] - b * rpb) << 16) | (unsigned)(cc[j] & 0xFFFF);
                rank[j] = atomicAdd(&lcnt[b], 1);
            }
        } else {
#pragma unroll
            for (int j = 0; j < PER; ++j) {
                long long e = e0 + j;
                if (e < E) {
                    int r = g_idx(edge, e, is64);
                    int c = g_idx(edge, (long long)E + e, is64);
                    int b = r / rpb;
                    bkt[j] = b;
                    enc[j] = ((unsigned)(r - b * rpb) << 16) | (unsigned)(c & 0xFFFF);
                    rank[j] = atomicAdd(&lcnt[b], 1);
                } else bkt[j] = -1;
            }
        }
        __syncthreads();
        if (t < NBKT) lbase[t] = atomicAdd(&bucketcnt[t], lcnt[t]);
        __syncthreads();
#pragma unroll
        for (int j = 0; j < PER; ++j) {
            if (bkt[j] >= 0) {
                int pos = lbase[bkt[j]] + rank[j];
                if (pos < BCAP)
                    bucketbuf[(size_t)bkt[j] * BCAP + pos] = enc[j];
            }
        }
    }
}

// -------- phase B (fused): CSR sort + degrees + h0/g0 init + w1t transpose --------
__global__ __launch_bounds__(512) void k_bsort(
        const unsigned* __restrict__ bucketbuf, const int* __restrict__ bucketcnt,
        int* __restrict__ rowptr, float* __restrict__ di2, float* __restrict__ rdinv,
        unsigned short* __restrict__ cols16,
        const void* emb, unsigned* __restrict__ h0, unsigned* __restrict__ g0, int SST,
        const void* w1, unsigned short* __restrict__ w1t,
        int N, int rpb, const int* flags) {
    __shared__ int hist[512];
    __shared__ float dvs[512];
    int b = blockIdx.x;
    int t = threadIdx.x;
    int f32 = flags[2];
    int base = 0, cnt = 0, total = 0;
    for (int i = 0; i < NBKT; ++i) {
        int v = bucketcnt[i];
        if (v > BCAP) v = BCAP;
        if (i < b) base += v;
        if (i == b) cnt = v;
        total += v;
    }
    int r0 = b * rpb;
    int rows = N - r0;
    if (rows > rpb) rows = rpb;
    if (rows < 0) rows = 0;

    hist[t] = 0;
    __syncthreads();
    const unsigned* buf = bucketbuf + (size_t)b * BCAP;
    for (int i = t; i < cnt; i += 512) atomicAdd(&hist[buf[i] >> 16], 1);
    __syncthreads();
    int v = hist[t];
    __syncthreads();
    for (int off = 1; off < 512; off <<= 1) {
        int x = (t >= off) ? hist[t - off] : 0;
        __syncthreads();
        hist[t] += x;
        __syncthreads();
    }
    int excl = hist[t] - v;
    float dv = (v > 0) ? rsqrtf((float)v) : 0.0f;
    dvs[t] = dv;
    if (t < rows) {
        int r = r0 + t;
        rowptr[r] = base + excl;
        di2[r] = dv * dv;
        rdinv[r] = (v > 0) ? sqrtf((float)v) : 0.0f;
    }
    if (b == NBKT - 1 && t == 0) rowptr[N] = total;
    __syncthreads();
    hist[t] = base + excl;  // global cursor per owned row
    __syncthreads();
    for (int i = t; i < cnt; i += 512) {
        unsigned u = buf[i];
        int pos = atomicAdd(&hist[u >> 16], 1);
        cols16[pos] = (unsigned short)(u & 0xFFFF);
    }

    // h0/g0 init for owned rows (slice-major), using LDS dvs
    for (int i = t; i < rows * 64; i += 512) {
        int nl = i >> 6, w = i & 63;
        int n = r0 + nl;
        long long src = (long long)n * C + 2 * w;
        float lo = g_flt(emb, src, f32);
        float hi = g_flt(emb, src + 1, f32);
        size_t o = (size_t)(w >> 5) * SST + (size_t)n * 32 + (w & 31);
        h0[o] = packbf(lo, hi);
        float d = dvs[nl];
        g0[o] = packbf(lo * d, hi * d);
    }

    // distributed w1t transpose: block b handles elements [b*256, b*256+256)
    if (t < 256) {
        int i = b * 256 + t;
        int k = i >> 7, n = i & 127;
        w1t[n * 256 + k] = f2bf(g_flt(w1, i, f32));
    }
}

// -------- propagation (2-slice, octet-per-node-slice, 8 neighbors/trip, no shuffles) --------
__global__ void k_layer(const int* __restrict__ rowptr, const unsigned short* __restrict__ cols16,
                        const uint4* __restrict__ gin, uint4* __restrict__ gout,
                        const float* __restrict__ di2, int N, int SSTU4) {
    int slice = blockIdx.x & 1;
    int node = (blockIdx.x >> 1) * 32 + (threadIdx.x >> 3);
    if (node >= N) return;
    int l8 = threadIdx.x & 7;
    const uint4* gs = gin + (size_t)slice * SSTU4;
    int p = rowptr[node];
    int end = rowptr[node + 1];
    float a0 = 0.f, a1 = 0.f, a2 = 0.f, a3 = 0.f;
    float a4 = 0.f, a5 = 0.f, a6 = 0.f, a7 = 0.f;
    for (int base = p; base < end; base += 8) {
        int c[8];
#pragma unroll
        for (int j = 0; j < 8; ++j) {
            int idx = base + j;
            int cv = cols16[idx];
            c[j] = (idx < end) ? cv : N;
        }
#pragma unroll
        for (int j = 0; j < 8; ++j) {
            uint4 v = gs[(size_t)c[j] * 8 + l8];
            a0 += bflo(v.x); a1 += bfhi(v.x);
            a2 += bflo(v.y); a3 += bfhi(v.y);
            a4 += bflo(v.z); a5 += bfhi(v.z);
            a6 += bflo(v.w); a7 += bfhi(v.w);
        }
    }
    float s = di2[node];
    uint4 o;
    o.x = packbf(a0 * s, a1 * s);
    o.y = packbf(a2 * s, a3 * s);
    o.z = packbf(a4 * s, a5 * s);
    o.w = packbf(a6 * s, a7 * s);
    gout[(size_t)slice * SSTU4 + (size_t)node * 8 + l8] = o;
}

// -------- layer 3 fused: fin(node-major) = 0.25*(h0 + rdinv*(g1 + g2 + di2*sum)) --------
__global__ void k_layer3(const int* __restrict__ rowptr, const unsigned short* __restrict__ cols16,
                         const uint4* __restrict__ gin /*g2*/, const uint4* __restrict__ h0,
                         const uint4* __restrict__ g1, uint4* __restrict__ fin,
                         const float* __restrict__ di2, const float* __restrict__ rdinv,
                         int N, int SSTU4) {
    int slice = blockIdx.x & 1;
    int node = (blockIdx.x >> 1) * 32 + (threadIdx.x >> 3);
    if (node >= N) return;
    int l8 = threadIdx.x & 7;
    size_t sb = (size_t)slice * SSTU4;
    const uint4* gs = gin + sb;
    int p = rowptr[node];
    int end = rowptr[node + 1];
    float a0 = 0.f, a1 = 0.f, a2 = 0.f, a3 = 0.f;
    float a4 = 0.f, a5 = 0.f, a6 = 0.f, a7 = 0.f;
    for (int base = p; base < end; base += 8) {
        int c[8];
#pragma unroll
        for (int j = 0; j < 8; ++j) {
            int idx = base + j;
            int cv = cols16[idx];
            c[j] = (idx < end) ? cv : N;
        }
#pragma unroll
        for (int j = 0; j < 8; ++j) {
            uint4 v = gs[(size_t)c[j] * 8 + l8];
            a0 += bflo(v.x); a1 += bfhi(v.x);
            a2 += bflo(v.y); a3 += bfhi(v.y);
            a4 += bflo(v.z); a5 += bfhi(v.z);
            a6 += bflo(v.w); a7 += bfhi(v.w);
        }
    }
    float s = di2[node];
    float rd = rdinv[node];
    size_t ro = (size_t)node * 8 + l8;
    uint4 x0 = h0[sb + ro];
    uint4 x1 = g1[sb + ro];
    uint4 x2 = gs[ro];
    uint4 o;
    o.x = packbf(0.25f * (bflo(x0.x) + rd * (bflo(x1.x) + bflo(x2.x) + s * a0)),
                 0.25f * (bfhi(x0.x) + rd * (bfhi(x1.x) + bfhi(x2.x) + s * a1)));
    o.y = packbf(0.25f * (bflo(x0.y) + rd * (bflo(x1.y) + bflo(x2.y) + s * a2)),
                 0.25f * (bfhi(x0.y) + rd * (bfhi(x1.y) + bfhi(x2.y) + s * a3)));
    o.z = packbf(0.25f * (bflo(x0.z) + rd * (bflo(x1.z) + bflo(x2.z) + s * a4)),
                 0.25f * (bfhi(x0.z) + rd * (bfhi(x1.z) + bfhi(x2.z) + s * a5)));
    o.w = packbf(0.25f * (bflo(x0.w) + rd * (bflo(x1.w) + bflo(x2.w) + s * a6)),
                 0.25f * (bfhi(x0.w) + rd * (bfhi(x1.w) + bfhi(x2.w) + s * a7)));
    fin[(size_t)node * 16 + slice * 8 + l8] = o;
}

// -------- MFMA head (fin node-major, uint4 staging; biases read raw) --------
__global__ void k_head(const uint4* __restrict__ fin, const void* n_id,
                       const unsigned short* __restrict__ w1t,
                       const void* b1, const void* w2, const void* b2,
                       float* __restrict__ out, int B, int NEG, const int* flags) {
    __shared__ unsigned short z[64][264];
    int t = threadIdx.x;
    int id64 = flags[1];
    int f32 = flags[2];
    int mbase = blockIdx.x * 64;

#pragma unroll
    for (int i = 0; i < 8; ++i) {
        int flat = i * 256 + t;        // 0..2047
        int m = flat >> 5;             // 0..63
        int q = flat & 31;             // uint4 slot within z row
        int gm = mbase + m;
        int r;
        if (gm < B) {
            r = (q < 16) ? g_idx(n_id, gm, id64) : g_idx(n_id, B + gm, id64);
        } else {
            int j = gm - B;
            r = (q < 16) ? g_idx(n_id, j / NEG, id64) : g_idx(n_id, 2 * B + j, id64);
        }
        uint4 v = fin[(size_t)r * 16 + (q & 15)];
        *(uint4*)((char*)&z[m][0] + q * 16) = v;
    }
    __syncthreads();

    int wave = t >> 6, lane = t & 63;
    int quad = lane >> 4, l16 = lane & 15;

    floatx4 acc[8] = {};
    bf16x8 a[8];
    const unsigned short* zrow = &z[wave * 16 + l16][0];
#pragma unroll
    for (int ks = 0; ks < 8; ++ks)
        a[ks] = *(const bf16x8*)(zrow + ks * 32 + quad * 8);

#pragma unroll
    for (int ks = 0; ks < 8; ++ks) {
#pragma unroll
        for (int nt = 0; nt < 8; ++nt) {
            bf16x8 b = *(const bf16x8*)(w1t + (nt * 16 + l16) * 256 + ks * 32 + quad * 8);
            acc[nt] = __builtin_amdgcn_mfma_f32_16x16x32_bf16(a[ks], b, acc[nt], 0, 0, 0);
        }
    }

    float s0 = 0.f, s1 = 0.f, s2 = 0.f, s3 = 0.f;
#pragma unroll
    for (int nt = 0; nt < 8; ++nt) {
        int col = nt * 16 + l16;
        float bb = g_flt(b1, col, f32), ww = g_flt(w2, col, f32);
        float v0 = acc[nt][0] + bb; v0 = (v0 > 0.f) ? v0 : 0.2f * v0; s0 += v0 * ww;
        float v1 = acc[nt][1] + bb; v1 = (v1 > 0.f) ? v1 : 0.2f * v1; s1 += v1 * ww;
        float v2 = acc[nt][2] + bb; v2 = (v2 > 0.f) ? v2 : 0.2f * v2; s2 += v2 * ww;
        float v3 = acc[nt][3] + bb; v3 = (v3 > 0.f) ? v3 : 0.2f * v3; s3 += v3 * ww;
    }
#pragma unroll
    for (int off = 1; off <= 8; off <<= 1) {
        s0 += __shfl_xor(s0, off, 64);
        s1 += __shfl_xor(s1, off, 64);
        s2 += __shfl_xor(s2, off, 64);
        s3 += __shfl_xor(s3, off, 64);
    }
    if (l16 == 0) {
        int rowbase = mbase + wave * 16 + quad * 4;
        float bb2 = g_flt(b2, 0, f32);
        out[rowbase + 0] = s0 + bb2;
        out[rowbase + 1] = s1 + bb2;
        out[rowbase + 2] = s2 + bb2;
        out[rowbase + 3] = s3 + bb2;
    }
}

extern "C" void kernel_launch(void* const* d_in, const int* in_sizes, int n_in,
                              void* d_out, int out_size, void* d_ws, size_t ws_size,
                              hipStream_t stream) {
    const void* edge_index = d_in[1];
    const void* n_id       = d_in[3];
    const void* id_embed   = d_in[5];
    const void* w1 = d_in[6];
    const void* b1 = d_in[7];
    const void* w2 = d_in[8];
    const void* b2 = d_in[9];
    float* out = (float*)d_out;

    const int E  = in_sizes[1] / 2;
    const int N  = in_sizes[5] / C;
    const int NEG = 5;
    const int B  = in_sizes[3] / (2 + NEG);
    const int n_out_rows = B + B * NEG;  // 24576
    const int SST = (N + 1) * 32;        // slice stride in u32 (2 slices)
    const int SSTU4 = (N + 1) * 8;       // slice stride in uint4
    const int NB = 2 * SST;              // u32 per slice-major buffer
    const int rpb = (N + NBKT - 1) / NBKT;  // 391 (<=512)

    size_t off = 0;
    auto alloc = [&](size_t nf) {
        char* p = (char*)d_ws + off * 4;
        off += (nf + 255) & ~(size_t)255;
        return p;
    };
    int*   flags     = (int*)alloc(8);
    int*   bucketcnt = (int*)alloc(NBKT);
    float* di2       = (float*)alloc(N);
    float* rdinv     = (float*)alloc(N);
    int*   rowptr    = (int*)alloc(N + 1);
    unsigned short* cols16 = (unsigned short*)alloc(((size_t)E + 16 + 1) / 2);
    unsigned* bucketbuf = (unsigned*)alloc((size_t)NBKT * BCAP);
    unsigned* h0     = (unsigned*)alloc(NB);
    unsigned* g0     = (unsigned*)alloc(NB);
    unsigned* g1     = (unsigned*)alloc(NB);
    unsigned* g2     = (unsigned*)alloc(NB);
    unsigned* fin    = (unsigned*)alloc((size_t)N * 64);
    unsigned short* w1t = (unsigned short*)alloc(256 * 128 / 2);

    const int BS = 256;
    k_detect<<<1, 192, 0, stream>>>(edge_index, n_id, id_embed, flags, g0, g1, g2,
                                    bucketcnt, N, SST);
    const int gridA = (E + BS * 8 - 1) / (BS * 8);
    k_bucketA<<<gridA, BS, 0, stream>>>(edge_index, E, rpb, flags, bucketbuf, bucketcnt);
    k_bsort<<<NBKT, 512, 0, stream>>>(bucketbuf, bucketcnt, rowptr, di2, rdinv, cols16,
                                      id_embed, h0, g0, SST, w1, w1t, N, rpb, flags);

    const int layer_grid = ((N + 31) / 32) * 2;
    k_layer<<<layer_grid, BS, 0, stream>>>(rowptr, cols16, (const uint4*)g0, (uint4*)g1,
                                           di2, N, SSTU4);
    k_layer<<<layer_grid, BS, 0, stream>>>(rowptr, cols16, (const uint4*)g1, (uint4*)g2,
                                           di2, N, SSTU4);
    k_layer3<<<layer_grid, BS, 0, stream>>>(rowptr, cols16, (const uint4*)g2, (const uint4*)h0,
                                            (const uint4*)g1, (uint4*)fin, di2, rdinv,
                                            N, SSTU4);

    k_head<<<n_out_rows / 64, BS, 0, stream>>>((const uint4*)fin, n_id, w1t, b1, w2, b2,
                                               out, B, NEG, flags);
}

// Round 20
// 216.717 us; speedup vs baseline: 1.0618x; 1.0618x over previous
//
#include <hip/hip_runtime.h>
#include <hip/hip_bf16.h>

#define C 128
#define NBKT 128
#define BCAP 8192

typedef __bf16 bf16x8 __attribute__((ext_vector_type(8)));
typedef float floatx4 __attribute__((ext_vector_type(4)));

// ---- manual bf16 helpers ----
__device__ __forceinline__ unsigned short f2bf(float f) {
    unsigned u = __float_as_uint(f);
    unsigned r = (u + 0x7FFFu + ((u >> 16) & 1u)) >> 16;
    return (unsigned short)r;
}
__device__ __forceinline__ float bflo(unsigned v) { return __uint_as_float(v << 16); }
__device__ __forceinline__ float bfhi(unsigned v) { return __uint_as_float(v & 0xFFFF0000u); }
__device__ __forceinline__ unsigned packbf(float lo, float hi) {
    return (unsigned)f2bf(lo) | ((unsigned)f2bf(hi) << 16);
}

// ---- dtype-flexible accessors ----
__device__ __forceinline__ int g_idx(const void* p, long long i, int is64) {
    if (is64) return (int)((const long long*)p)[i];
    return ((const int*)p)[i];
}
__device__ __forceinline__ float g_flt(const void* p, long long i, int isf32) {
    if (isf32) return ((const float*)p)[i];
    return __uint_as_float(((unsigned)((const unsigned short*)p)[i]) << 16);
}

// flags + zero row N (both slices) of g0,g1,g2 + zero bucketcnt
__global__ void k_detect(const void* edge, const void* nid, const void* emb, int* flags,
                         unsigned* g0, unsigned* g1, unsigned* g2, int* bucketcnt,
                         int N, int SST) {
    int t = threadIdx.x;  // 192 threads
    int buf = t >> 6, w = t & 63;
    size_t o = (size_t)(w >> 5) * SST + (size_t)N * 32 + (w & 31);
    if (buf == 0) g0[o] = 0;
    else if (buf == 1) g1[o] = 0;
    else g2[o] = 0;
    if (t < NBKT) bucketcnt[t] = 0;
    if (t < 64) {
        const unsigned* wrd = (const unsigned*)edge;
        const unsigned* nw = (const unsigned*)nid;
        int predA = (t < 32) ? (wrd[2 * t + 1] == 0u) : 1;
        int predB = (t < 32) ? (nw[2 * t + 1] == 0u) : 1;
        const unsigned short* h = (const unsigned short*)emb;
        int ex = (h[2 * t] >> 7) & 0xFF;
        int plaus = (ex >= 0x6C && ex <= 0x7F) ? 1 : 0;
        unsigned long long mA = __ballot(predA);
        unsigned long long mB = __ballot(predB);
        unsigned long long mP = __ballot(plaus);
        if (t == 0) {
            flags[0] = (mA == ~0ull) ? 1 : 0;
            flags[1] = (mB == ~0ull) ? 1 : 0;
            flags[2] = (__popcll(mP) < 32) ? 1 : 0;
        }
    }
}

// -------- phase A: bucket edges into 128 row-ranges; vectorized edge loads --------
__global__ void k_bucketA(const void* edge, int E, int rpb, const int* flags,
                          unsigned* __restrict__ bucketbuf, int* __restrict__ bucketcnt) {
    __shared__ int lcnt[NBKT];
    __shared__ int lbase[NBKT];
    int t = threadIdx.x;
    int is64 = flags[0];
    const int PER = 8;
    int chunkSz = blockDim.x * PER;
    long long stride = (long long)gridDim.x * chunkSz;
    for (long long base = (long long)blockIdx.x * chunkSz; base < E; base += stride) {
        if (t < NBKT) lcnt[t] = 0;
        __syncthreads();
        int bkt[PER], rank[PER];
        unsigned enc[PER];
        long long e0 = base + (long long)t * PER;
        int rr[PER], cc[PER];
        if (e0 + PER <= E) {
            if (is64) {
                const long long* pr = (const long long*)edge + e0;
                const long long* pc = (const long long*)edge + E + e0;
#pragma unroll
                for (int j = 0; j < PER; j += 2) {
                    longlong2 vr = *(const longlong2*)(pr + j);
                    longlong2 vc = *(const longlong2*)(pc + j);
                    rr[j] = (int)vr.x; rr[j + 1] = (int)vr.y;
                    cc[j] = (int)vc.x; cc[j + 1] = (int)vc.y;
                }
            } else {
                const int* pr = (const int*)edge + e0;
                const int* pc = (const int*)edge + E + e0;
#pragma unroll
                for (int j = 0; j < PER; j += 4) {
                    int4 vr = *(const int4*)(pr + j);
                    int4 vc = *(const int4*)(pc + j);
                    rr[j] = vr.x; rr[j + 1] = vr.y; rr[j + 2] = vr.z; rr[j + 3] = vr.w;
                    cc[j] = vc.x; cc[j + 1] = vc.y; cc[j + 2] = vc.z; cc[j + 3] = vc.w;
                }
            }
#pragma unroll
            for (int j = 0; j < PER; ++j) {
                int b = rr[j] / rpb;
                bkt[j] = b;
                enc[j] = ((unsigned)(rr[j] - b * rpb) << 16) | (unsigned)(cc[j] & 0xFFFF);
                rank[j] = atomicAdd(&lcnt[b], 1);
            }
        } else {
#pragma unroll
            for (int j = 0; j < PER; ++j) {
                long long e = e0 + j;
                if (e < E) {
                    int r = g_idx(edge, e, is64);
                    int c = g_idx(edge, (long long)E + e, is64);
                    int b = r / rpb;
                    bkt[j] = b;
                    enc[j] = ((unsigned)(r - b * rpb) << 16) | (unsigned)(c & 0xFFFF);
                    rank[j] = atomicAdd(&lcnt[b], 1);
                } else bkt[j] = -1;
            }
        }
        __syncthreads();
        if (t < NBKT) lbase[t] = atomicAdd(&bucketcnt[t], lcnt[t]);
        __syncthreads();
#pragma unroll
        for (int j = 0; j < PER; ++j) {
            if (bkt[j] >= 0) {
                int pos = lbase[bkt[j]] + rank[j];
                if (pos < BCAP)
                    bucketbuf[(size_t)bkt[j] * BCAP + pos] = enc[j];
            }
        }
    }
}

// -------- phase B: block b owns bucket b == rows [b*rpb, b*rpb+rpb) --------
__global__ __launch_bounds__(512) void k_bsort(
        const unsigned* __restrict__ bucketbuf, const int* __restrict__ bucketcnt,
        int* __restrict__ rowptr, float* __restrict__ dinv, float* __restrict__ di2,
        float* __restrict__ rdinv, unsigned short* __restrict__ cols16, int N, int rpb) {
    __shared__ int hist[512];
    int b = blockIdx.x;
    int t = threadIdx.x;
    int base = 0, cnt = 0, total = 0;
    for (int i = 0; i < NBKT; ++i) {
        int v = bucketcnt[i];
        if (v > BCAP) v = BCAP;
        if (i < b) base += v;
        if (i == b) cnt = v;
        total += v;
    }
    int r0 = b * rpb;
    int rows = N - r0;
    if (rows > rpb) rows = rpb;
    if (rows < 0) rows = 0;

    hist[t] = 0;
    __syncthreads();
    const unsigned* buf = bucketbuf + (size_t)b * BCAP;
    for (int i = t; i < cnt; i += 512) atomicAdd(&hist[buf[i] >> 16], 1);
    __syncthreads();
    int v = hist[t];
    __syncthreads();
    for (int off = 1; off < 512; off <<= 1) {
        int x = (t >= off) ? hist[t - off] : 0;
        __syncthreads();
        hist[t] += x;
        __syncthreads();
    }
    int excl = hist[t] - v;
    if (t < rows) {
        int r = r0 + t;
        rowptr[r] = base + excl;
        float fd = (float)v;
        float dv = (v > 0) ? rsqrtf(fd) : 0.0f;
        dinv[r] = dv;
        di2[r] = dv * dv;
        rdinv[r] = (v > 0) ? sqrtf(fd) : 0.0f;
    }
    if (b == NBKT - 1 && t == 0) rowptr[N] = total;
    __syncthreads();
    hist[t] = base + excl;  // global cursor per owned row
    __syncthreads();
    for (int i = t; i < cnt; i += 512) {
        unsigned u = buf[i];
        int pos = atomicAdd(&hist[u >> 16], 1);
        cols16[pos] = (unsigned short)(u & 0xFFFF);
    }
}

// -------- init + prep fused: h0/g0 (slice-major) init, W1T transpose, bias copies --------
__global__ void k_initprep(const void* emb, const float* __restrict__ dinv,
                           unsigned* __restrict__ h0, unsigned* __restrict__ g0,
                           int n2, int SST,
                           const void* w1, const void* b1, const void* w2, const void* b2,
                           unsigned short* __restrict__ w1t, float* __restrict__ b1f,
                           float* __restrict__ w2f, float* __restrict__ b2f, const int* flags) {
    int i = blockIdx.x * blockDim.x + threadIdx.x;
    int f32 = flags[2];
    if (i < n2) {
        float lo = g_flt(emb, 2LL * i, f32);
        float hi = g_flt(emb, 2LL * i + 1, f32);
        int n = i >> 6, w = i & 63;
        size_t o = (size_t)(w >> 5) * SST + (size_t)n * 32 + (w & 31);
        h0[o] = packbf(lo, hi);
        float dv = dinv[n];
        g0[o] = packbf(lo * dv, hi * dv);
    }
    if (i < 256 * 128) {
        int k = i >> 7, n = i & 127;
        w1t[n * 256 + k] = f2bf(g_flt(w1, i, f32));
    }
    if (i < 128) {
        b1f[i] = g_flt(b1, i, f32);
        w2f[i] = g_flt(w2, i, f32);
    }
    if (i == 0) b2f[0] = g_flt(b2, 0, f32);
}

// -------- propagation (2-slice, octet-per-node-slice, 8 neighbors/trip, no shuffles) --------
__global__ void k_layer(const int* __restrict__ rowptr, const unsigned short* __restrict__ cols16,
                        const uint4* __restrict__ gin, uint4* __restrict__ gout,
                        const float* __restrict__ di2, int N, int SSTU4) {
    int slice = blockIdx.x & 1;
    int node = (blockIdx.x >> 1) * 32 + (threadIdx.x >> 3);
    if (node >= N) return;
    int l8 = threadIdx.x & 7;
    const uint4* gs = gin + (size_t)slice * SSTU4;
    int p = rowptr[node];
    int end = rowptr[node + 1];
    float a0 = 0.f, a1 = 0.f, a2 = 0.f, a3 = 0.f;
    float a4 = 0.f, a5 = 0.f, a6 = 0.f, a7 = 0.f;
    for (int base = p; base < end; base += 8) {
        int c[8];
#pragma unroll
        for (int j = 0; j < 8; ++j) {
            int idx = base + j;
            int cv = cols16[idx];
            c[j] = (idx < end) ? cv : N;
        }
#pragma unroll
        for (int j = 0; j < 8; ++j) {
            uint4 v = gs[(size_t)c[j] * 8 + l8];
            a0 += bflo(v.x); a1 += bfhi(v.x);
            a2 += bflo(v.y); a3 += bfhi(v.y);
            a4 += bflo(v.z); a5 += bfhi(v.z);
            a6 += bflo(v.w); a7 += bfhi(v.w);
        }
    }
    float s = di2[node];
    uint4 o;
    o.x = packbf(a0 * s, a1 * s);
    o.y = packbf(a2 * s, a3 * s);
    o.z = packbf(a4 * s, a5 * s);
    o.w = packbf(a6 * s, a7 * s);
    gout[(size_t)slice * SSTU4 + (size_t)node * 8 + l8] = o;
}

// -------- layer 3 fused: fin(node-major) = 0.25*(h0 + rdinv*(g1 + g2 + di2*sum)) --------
__global__ void k_layer3(const int* __restrict__ rowptr, const unsigned short* __restrict__ cols16,
                         const uint4* __restrict__ gin /*g2*/, const uint4* __restrict__ h0,
                         const uint4* __restrict__ g1, uint4* __restrict__ fin,
                         const float* __restrict__ di2, const float* __restrict__ rdinv,
                         int N, int SSTU4) {
    int slice = blockIdx.x & 1;
    int node = (blockIdx.x >> 1) * 32 + (threadIdx.x >> 3);
    if (node >= N) return;
    int l8 = threadIdx.x & 7;
    size_t sb = (size_t)slice * SSTU4;
    const uint4* gs = gin + sb;
    int p = rowptr[node];
    int end = rowptr[node + 1];
    float a0 = 0.f, a1 = 0.f, a2 = 0.f, a3 = 0.f;
    float a4 = 0.f, a5 = 0.f, a6 = 0.f, a7 = 0.f;
    for (int base = p; base < end; base += 8) {
        int c[8];
#pragma unroll
        for (int j = 0; j < 8; ++j) {
            int idx = base + j;
            int cv = cols16[idx];
            c[j] = (idx < end) ? cv : N;
        }
#pragma unroll
        for (int j = 0; j < 8; ++j) {
            uint4 v = gs[(size_t)c[j] * 8 + l8];
            a0 += bflo(v.x); a1 += bfhi(v.x);
            a2 += bflo(v.y); a3 += bfhi(v.y);
            a4 += bflo(v.z); a5 += bfhi(v.z);
            a6 += bflo(v.w); a7 += bfhi(v.w);
        }
    }
    float s = di2[node];
    float rd = rdinv[node];
    size_t ro = (size_t)node * 8 + l8;
    uint4 x0 = h0[sb + ro];
    uint4 x1 = g1[sb + ro];
    uint4 x2 = gs[ro];
    uint4 o;
    o.x = packbf(0.25f * (bflo(x0.x) + rd * (bflo(x1.x) + bflo(x2.x) + s * a0)),
                 0.25f * (bfhi(x0.x) + rd * (bfhi(x1.x) + bfhi(x2.x) + s * a1)));
    o.y = packbf(0.25f * (bflo(x0.y) + rd * (bflo(x1.y) + bflo(x2.y) + s * a2)),
                 0.25f * (bfhi(x0.y) + rd * (bfhi(x1.y) + bfhi(x2.y) + s * a3)));
    o.z = packbf(0.25f * (bflo(x0.z) + rd * (bflo(x1.z) + bflo(x2.z) + s * a4)),
                 0.25f * (bfhi(x0.z) + rd * (bfhi(x1.z) + bfhi(x2.z) + s * a5)));
    o.w = packbf(0.25f * (bflo(x0.w) + rd * (bflo(x1.w) + bflo(x2.w) + s * a6)),
                 0.25f * (bfhi(x0.w) + rd * (bfhi(x1.w) + bfhi(x2.w) + s * a7)));
    fin[(size_t)node * 16 + slice * 8 + l8] = o;
}

// -------- MFMA head (fin node-major, uint4 staging) --------
__global__ void k_head(const uint4* __restrict__ fin, const void* n_id,
                       const unsigned short* __restrict__ w1t,
                       const float* __restrict__ b1f, const float* __restrict__ w2f,
                       const float* __restrict__ b2f,
                       float* __restrict__ out, int B, int NEG, const int* flags) {
    __shared__ unsigned short z[64][264];
    int t = threadIdx.x;
    int id64 = flags[1];
    int mbase = blockIdx.x * 64;

#pragma unroll
    for (int i = 0; i < 8; ++i) {
        int flat = i * 256 + t;        // 0..2047
        int m = flat >> 5;             // 0..63
        int q = flat & 31;             // uint4 slot within z row
        int gm = mbase + m;
        int r;
        if (gm < B) {
            r = (q < 16) ? g_idx(n_id, gm, id64) : g_idx(n_id, B + gm, id64);
        } else {
            int j = gm - B;
            r = (q < 16) ? g_idx(n_id, j / NEG, id64) : g_idx(n_id, 2 * B + j, id64);
        }
        uint4 v = fin[(size_t)r * 16 + (q & 15)];
        *(uint4*)((char*)&z[m][0] + q * 16) = v;
    }
    __syncthreads();

    int wave = t >> 6, lane = t & 63;
    int quad = lane >> 4, l16 = lane & 15;

    floatx4 acc[8] = {};
    bf16x8 a[8];
    const unsigned short* zrow = &z[wave * 16 + l16][0];
#pragma unroll
    for (int ks = 0; ks < 8; ++ks)
        a[ks] = *(const bf16x8*)(zrow + ks * 32 + quad * 8);

#pragma unroll
    for (int ks = 0; ks < 8; ++ks) {
#pragma unroll
        for (int nt = 0; nt < 8; ++nt) {
            bf16x8 b = *(const bf16x8*)(w1t + (nt * 16 + l16) * 256 + ks * 32 + quad * 8);
            acc[nt] = __builtin_amdgcn_mfma_f32_16x16x32_bf16(a[ks], b, acc[nt], 0, 0, 0);
        }
    }

    float s0 = 0.f, s1 = 0.f, s2 = 0.f, s3 = 0.f;
#pragma unroll
    for (int nt = 0; nt < 8; ++nt) {
        int col = nt * 16 + l16;
        float bb = b1f[col], ww = w2f[col];
        float v0 = acc[nt][0] + bb; v0 = (v0 > 0.f) ? v0 : 0.2f * v0; s0 += v0 * ww;
        float v1 = acc[nt][1] + bb; v1 = (v1 > 0.f) ? v1 : 0.2f * v1; s1 += v1 * ww;
        float v2 = acc[nt][2] + bb; v2 = (v2 > 0.f) ? v2 : 0.2f * v2; s2 += v2 * ww;
        float v3 = acc[nt][3] + bb; v3 = (v3 > 0.f) ? v3 : 0.2f * v3; s3 += v3 * ww;
    }
#pragma unroll
    for (int off = 1; off <= 8; off <<= 1) {
        s0 += __shfl_xor(s0, off, 64);
        s1 += __shfl_xor(s1, off, 64);
        s2 += __shfl_xor(s2, off, 64);
        s3 += __shfl_xor(s3, off, 64);
    }
    if (l16 == 0) {
        int rowbase = mbase + wave * 16 + quad * 4;
        float bb2 = b2f[0];
        out[rowbase + 0] = s0 + bb2;
        out[rowbase + 1] = s1 + bb2;
        out[rowbase + 2] = s2 + bb2;
        out[rowbase + 3] = s3 + bb2;
    }
}

extern "C" void kernel_launch(void* const* d_in, const int* in_sizes, int n_in,
                              void* d_out, int out_size, void* d_ws, size_t ws_size,
                              hipStream_t stream) {
    const void* edge_index = d_in[1];
    const void* n_id       = d_in[3];
    const void* id_embed   = d_in[5];
    const void* w1 = d_in[6];
    const void* b1 = d_in[7];
    const void* w2 = d_in[8];
    const void* b2 = d_in[9];
    float* out = (float*)d_out;

    const int E  = in_sizes[1] / 2;
    const int N  = in_sizes[5] / C;
    const int NEG = 5;
    const int B  = in_sizes[3] / (2 + NEG);
    const int n_out_rows = B + B * NEG;  // 24576
    const int SST = (N + 1) * 32;        // slice stride in u32 (2 slices)
    const int SSTU4 = (N + 1) * 8;       // slice stride in uint4
    const int NB = 2 * SST;              // u32 per slice-major buffer
    const int rpb = (N + NBKT - 1) / NBKT;  // 391 (<=512)

    size_t off = 0;
    auto alloc = [&](size_t nf) {
        char* p = (char*)d_ws + off * 4;
        off += (nf + 255) & ~(size_t)255;
        return p;
    };
    int*   flags     = (int*)alloc(8);
    int*   bucketcnt = (int*)alloc(NBKT);
    float* dinv      = (float*)alloc(N);
    float* di2       = (float*)alloc(N);
    float* rdinv     = (float*)alloc(N);
    int*   rowptr    = (int*)alloc(N + 1);
    unsigned short* cols16 = (unsigned short*)alloc(((size_t)E + 16 + 1) / 2);
    unsigned* bucketbuf = (unsigned*)alloc((size_t)NBKT * BCAP);
    unsigned* h0     = (unsigned*)alloc(NB);
    unsigned* g0     = (unsigned*)alloc(NB);
    unsigned* g1     = (unsigned*)alloc(NB);
    unsigned* g2     = (unsigned*)alloc(NB);
    unsigned* fin    = (unsigned*)alloc((size_t)N * 64);
    unsigned short* w1t = (unsigned short*)alloc(256 * 128 / 2);
    float* b1f       = (float*)alloc(C);
    float* w2f       = (float*)alloc(C);
    float* b2f       = (float*)alloc(8);

    const int BS = 256;
    k_detect<<<1, 192, 0, stream>>>(edge_index, n_id, id_embed, flags, g0, g1, g2,
                                    bucketcnt, N, SST);
    const int gridA = (E + BS * 8 - 1) / (BS * 8);
    k_bucketA<<<gridA, BS, 0, stream>>>(edge_index, E, rpb, flags, bucketbuf, bucketcnt);
    k_bsort<<<NBKT, 512, 0, stream>>>(bucketbuf, bucketcnt, rowptr, dinv, di2, rdinv,
                                      cols16, N, rpb);
    k_initprep<<<(N * 64 + BS - 1) / BS, BS, 0, stream>>>(
        id_embed, dinv, h0, g0, N * 64, SST, w1, b1, w2, b2, w1t, b1f, w2f, b2f, flags);

    const int layer_grid = ((N + 31) / 32) * 2;
    k_layer<<<layer_grid, BS, 0, stream>>>(rowptr, cols16, (const uint4*)g0, (uint4*)g1,
                                           di2, N, SSTU4);
    k_layer<<<layer_grid, BS, 0, stream>>>(rowptr, cols16, (const uint4*)g1, (uint4*)g2,
                                           di2, N, SSTU4);
    k_layer3<<<layer_grid, BS, 0, stream>>>(rowptr, cols16, (const uint4*)g2, (const uint4*)h0,
                                            (const uint4*)g1, (uint4*)fin, di2, rdinv,
                                            N, SSTU4);

    k_head<<<n_out_rows / 64, BS, 0, stream>>>((const uint4*)fin, n_id, w1t, b1f, w2f, b2f,
                                               out, B, NEG, flags);
}